// Round 1
// baseline (622.318 us; speedup 1.0000x reference)
//
#include <hip/hip_runtime.h>

#define B_SZ 512
#define KHOP 2
#define NNB  32
#define F0   512
#define C1   4
#define F1   16
#define C2   32
#define NCLS 40

#define EPS_BN   1e-5f
#define EPS_NORM 1e-7f

__device__ __forceinline__ float softsignf(float v) { return v / (1.0f + fabsf(v)); }

// ---------------------------------------------------------------------------
// Kernel 1: per (b,k) block. Computes h_raw[b,k,d,e] (pre-BN) and
// nbs[b,k,d,e] = sum_n softsign(bn(nbh))  (nbh BN is local to (b,k) -> fused).
//
// LDS layout (bytes):
//   [0,65536)      nb[32][512]         (phase 1/2)
//   [0,73728)      xgT[512][36]        (phase 3, overwrites nb)
//   [0,32768)      red_nb[4][64][32]   (phase 3b, overwrites xgT)
//   [32768,33792)  red_h[4][64]
//   [33792,41984)  nbh[4][32][16]
//   [73728,75776)  x[512]
//   [75776,77824)  s[512] -> xg_x[512] in phase 3
// ---------------------------------------------------------------------------
#define SMEM_MAIN 77824

__global__ __launch_bounds__(256, 2) void k_main(
    const float* __restrict__ xg_, const float* __restrict__ nbg,
    const float* __restrict__ W1, const float* __restrict__ g1,
    const float* __restrict__ b1,
    float* __restrict__ h_raw, float* __restrict__ nbs_out)
{
    extern __shared__ char smem[];
    float* nb     = (float*)smem;
    float* xgT    = (float*)smem;
    float* red_nb = (float*)smem;
    float* red_h  = (float*)(smem + 32768);
    float* nbh    = (float*)(smem + 33792);
    float* xl     = (float*)(smem + 73728);
    float* sl     = (float*)(smem + 75776);

    const int t    = threadIdx.x;
    const int pair = blockIdx.x;          // b*2 + k
    const int b    = pair >> 1, k = pair & 1;

    // ---- phase 1: stage neighbor tile + x ----
    {
        const float4* src = (const float4*)(nbg + (size_t)pair * (NNB * F0));
        float4* dst = (float4*)nb;
        #pragma unroll
        for (int i = 0; i < (NNB * F0 / 4) / 256; ++i)
            dst[t + 256 * i] = src[t + 256 * i];
        const float4* xs = (const float4*)(xg_ + b * F0);
        if (t < F0 / 4) ((float4*)xl)[t] = xs[t];
    }
    __syncthreads();
    // s[g] = sum_n nb[n][g]
    for (int g = t; g < F0; g += 256) {
        float a = 0.f;
        #pragma unroll
        for (int n = 0; n < NNB; ++n) a += nb[n * F0 + g];
        sl[g] = a;
    }
    __syncthreads();

    // ---- phase 2: per-thread 2 columns g. V[f,g]=sgnroot(x_f*s_g + x_g*s_f) ----
    const int g0 = t, g1i = t + 256;
    const float xv0 = xl[g0], xv1 = xl[g1i];
    const float sv0 = sl[g0], sv1 = sl[g1i];
    float accD0 = 0.f, accD1 = 0.f, accX0 = 0.f, accX1 = 0.f;
    float accN0[NNB], accN1[NNB];
    #pragma unroll
    for (int n = 0; n < NNB; ++n) { accN0[n] = 0.f; accN1[n] = 0.f; }

    for (int f = 0; f < F0; f += 4) {
        float4 xf = *(const float4*)(xl + f);
        float4 sf = *(const float4*)(sl + f);
        const float* xfp = (const float*)&xf;
        const float* sfp = (const float*)&sf;
        float v0[4], v1[4];
        #pragma unroll
        for (int i = 0; i < 4; ++i) {
            float r0 = xfp[i] * sv0 + xv0 * sfp[i];
            float r1 = xfp[i] * sv1 + xv1 * sfp[i];
            float a0 = sqrtf(fabsf(r0));
            float a1 = sqrtf(fabsf(r1));
            accD0 += a0; accD1 += a1;
            v0[i] = copysignf(a0, r0);
            v1[i] = copysignf(a1, r1);
            accX0 += xfp[i] * v0[i];
            accX1 += xfp[i] * v1[i];
        }
        #pragma unroll
        for (int n = 0; n < NNB; ++n) {
            float4 q = *(const float4*)(nb + n * F0 + f);
            const float* qp = (const float*)&q;
            accN0[n] += qp[0] * v0[0] + qp[1] * v0[1] + qp[2] * v0[2] + qp[3] * v0[3];
            accN1[n] += qp[0] * v1[0] + qp[1] * v1[1] + qp[2] * v1[2] + qp[3] * v1[3];
        }
    }
    const float id0 = 1.0f / (accD0 + EPS_NORM);
    const float id1 = 1.0f / (accD1 + EPS_NORM);
    __syncthreads();                     // all reads of nb/xl/sl done
    #pragma unroll
    for (int n = 0; n < NNB; ++n) {
        xgT[g0 * 36 + n]  = accN0[n] * id0;
        xgT[g1i * 36 + n] = accN1[n] * id1;
    }
    sl[g0]  = accX0 * id0;               // xg_x (column-normalized)
    sl[g1i] = accX1 * id1;
    __syncthreads();

    // ---- phase 3: nbh[n,d,e] = sum_g xgT[g][n]*W1[d,g,e]; h = sum_g xg_x[g]*W1 ----
    const int de = t & 63;
    const int dd = de >> 4, ee = de & 15;
    const int gs = t >> 6;               // g-slice 0..3 (128 g each)
    const float* W1p = W1 + k * (C1 * F0 * F1) + dd * (F0 * F1) + ee;
    float accn[NNB];
    #pragma unroll
    for (int n = 0; n < NNB; ++n) accn[n] = 0.f;
    float acch = 0.f;
    const int gbeg = gs * 128;
    for (int gi = 0; gi < 128; ++gi) {
        const int g = gbeg + gi;
        const float w = W1p[g * F1];
        acch += sl[g] * w;
        const float* row = xgT + g * 36;
        #pragma unroll
        for (int n4 = 0; n4 < 8; ++n4) {
            float4 q = *(const float4*)(row + n4 * 4);
            accn[n4 * 4 + 0] += q.x * w;
            accn[n4 * 4 + 1] += q.y * w;
            accn[n4 * 4 + 2] += q.z * w;
            accn[n4 * 4 + 3] += q.w * w;
        }
    }
    __syncthreads();                     // xgT reads complete before overwrite
    #pragma unroll
    for (int n = 0; n < NNB; ++n) red_nb[(gs * 64 + de) * 32 + n] = accn[n];
    red_h[gs * 64 + de] = acch;
    __syncthreads();

    if (t < 64)
        h_raw[pair * 64 + t] = red_h[t] + red_h[64 + t] + red_h[128 + t] + red_h[192 + t];

    {   // gather 4 slices -> nbh[d][n][e]
        const int de2 = t & 63, np8 = t >> 6;
        const int d2 = de2 >> 4, e2 = de2 & 15;
        #pragma unroll
        for (int j = 0; j < 8; ++j) {
            const int n = np8 * 8 + j;
            float v = red_nb[(0   + de2) * 32 + n] + red_nb[(64  + de2) * 32 + n]
                    + red_nb[(128 + de2) * 32 + n] + red_nb[(192 + de2) * 32 + n];
            nbh[(d2 * NNB + n) * F1 + e2] = v;
        }
    }
    __syncthreads();

    // ---- nbh BN (per (b,d) over n,e = 512 vals) + softsign + sum over n ----
    const int wv = t >> 6, lane = t & 63;    // wave wv handles d = wv
    float vals[8];
    float s1 = 0.f, s2 = 0.f;
    #pragma unroll
    for (int j = 0; j < 8; ++j) {
        float v = nbh[wv * 512 + lane + 64 * j];
        vals[j] = v; s1 += v; s2 += v * v;
    }
    #pragma unroll
    for (int off = 32; off >= 1; off >>= 1) {
        s1 += __shfl_xor(s1, off);
        s2 += __shfl_xor(s2, off);
    }
    const float mean = s1 * (1.f / 512.f);
    const float var  = s2 * (1.f / 512.f) - mean * mean;
    const float A    = g1[k * C1 + wv] * rsqrtf(var + EPS_BN);
    const float Bc   = b1[k * C1 + wv] - mean * A;
    float nbse = 0.f;
    #pragma unroll
    for (int j = 0; j < 8; ++j) nbse += softsignf(vals[j] * A + Bc);
    // lane's 8 vals share e = lane&15; sum over n -> reduce lanes l,l^16,l^32,l^48
    nbse += __shfl_xor(nbse, 16);
    nbse += __shfl_xor(nbse, 32);
    if (lane < 16) nbs_out[pair * 64 + wv * 16 + lane] = nbse;
}

// ---------------------------------------------------------------------------
// Kernel 2: global BN stats for h over (b,e) per (k,d). Writes affine (A,B).
// ---------------------------------------------------------------------------
__global__ __launch_bounds__(256) void k_hstats(
    const float* __restrict__ h_rawg, const float* __restrict__ g1,
    const float* __restrict__ b1, float* __restrict__ hstats)
{
    const int kd = blockIdx.x;           // k*4+d
    const int k = kd >> 2, d = kd & 3;
    float s1 = 0.f, s2 = 0.f;
    for (int i = threadIdx.x; i < B_SZ * F1; i += 256) {
        const int bb = i >> 4, e = i & 15;
        float v = h_rawg[(bb * 2 + k) * 64 + d * 16 + e];
        s1 += v; s2 += v * v;
    }
    #pragma unroll
    for (int off = 32; off >= 1; off >>= 1) { s1 += __shfl_xor(s1, off); s2 += __shfl_xor(s2, off); }
    __shared__ float r1[4], r2[4];
    if ((threadIdx.x & 63) == 0) { r1[threadIdx.x >> 6] = s1; r2[threadIdx.x >> 6] = s2; }
    __syncthreads();
    if (threadIdx.x == 0) {
        float S1 = r1[0] + r1[1] + r1[2] + r1[3];
        float S2 = r2[0] + r2[1] + r2[2] + r2[3];
        float mean = S1 * (1.f / 8192.f);
        float var  = S2 * (1.f / 8192.f) - mean * mean;
        float A = g1[kd] * rsqrtf(var + EPS_BN);
        hstats[kd] = A;
        hstats[8 + kd] = b1[kd] - mean * A;
    }
}

// ---------------------------------------------------------------------------
// Kernel 3: per (b,k) wave: softsign(bn(h)), fadj2 (16x16), xg2, W2 -> h2_raw
// ---------------------------------------------------------------------------
__global__ __launch_bounds__(256) void k_stage2(
    const float* __restrict__ h_rawg, const float* __restrict__ nbsg,
    const float* __restrict__ hstats, const float* __restrict__ W2,
    float* __restrict__ h2_raw)
{
    __shared__ float hl[4][64], nl[4][64], fl[4][256], xg2l[4][64];
    const int t = threadIdx.x, wv = t >> 6, l = t & 63;
    const int pair = blockIdx.x * 4 + wv;
    const int k = pair & 1;
    const int d = l >> 4;
    float hv = h_rawg[pair * 64 + l];
    hl[wv][l] = softsignf(hv * hstats[k * 4 + d] + hstats[8 + k * 4 + d]);
    nl[wv][l] = nbsg[pair * 64 + l];
    __syncthreads();
    const int gcol = l & 15;
    float raw[4];
    #pragma unroll
    for (int j = 0; j < 4; ++j) {
        const int idx = l + 64 * j;       // idx = f*16+g (g == gcol)
        const int f = idx >> 4;
        float a = 0.f;
        #pragma unroll
        for (int c = 0; c < 4; ++c) a += hl[wv][c * 16 + f] * nl[wv][c * 16 + gcol];
        raw[j] = a;
        fl[wv][idx] = a;
    }
    __syncthreads();
    float w4[4]; float Dp = 0.f;
    #pragma unroll
    for (int j = 0; j < 4; ++j) {
        const int idx = l + 64 * j;
        const int f = idx >> 4;
        float v = raw[j] + fl[wv][gcol * 16 + f];   // symmetrize
        float a = sqrtf(fabsf(v));
        Dp += a;
        w4[j] = copysignf(a, v);
    }
    Dp += __shfl_xor(Dp, 16);   // column sum over f (lanes sharing gcol)
    Dp += __shfl_xor(Dp, 32);
    const float invD = 1.f / (Dp + EPS_NORM);
    __syncthreads();            // transposed reads done before overwrite
    #pragma unroll
    for (int j = 0; j < 4; ++j) fl[wv][l + 64 * j] = w4[j] * invD;
    __syncthreads();
    {
        const int c = l >> 4;
        float a = 0.f;
        #pragma unroll
        for (int f = 0; f < 16; ++f) a += hl[wv][c * 16 + f] * fl[wv][f * 16 + gcol];
        xg2l[wv][c * 16 + gcol] = a;
    }
    __syncthreads();
    if (l < 32) {
        const float* W2p = W2 + k * (C2 * C1 * F1) + l * (C1 * F1);
        float a = 0.f;
        #pragma unroll
        for (int i = 0; i < 64; ++i) a += xg2l[wv][i] * W2p[i];
        h2_raw[pair * 32 + l] = a;
    }
}

// ---------------------------------------------------------------------------
// Kernel 4: global BN stats for h2 over b per (k,d=32)
// ---------------------------------------------------------------------------
__global__ __launch_bounds__(256) void k_h2stats(
    const float* __restrict__ h2_raw, const float* __restrict__ g2,
    const float* __restrict__ b2, float* __restrict__ h2st)
{
    const int kd = blockIdx.x;           // k*32+d
    const int k = kd >> 5, d = kd & 31;
    float s1 = 0.f, s2 = 0.f;
    for (int bb = threadIdx.x; bb < B_SZ; bb += 256) {
        float v = h2_raw[(bb * 2 + k) * 32 + d];
        s1 += v; s2 += v * v;
    }
    #pragma unroll
    for (int off = 32; off >= 1; off >>= 1) { s1 += __shfl_xor(s1, off); s2 += __shfl_xor(s2, off); }
    __shared__ float r1[4], r2[4];
    if ((threadIdx.x & 63) == 0) { r1[threadIdx.x >> 6] = s1; r2[threadIdx.x >> 6] = s2; }
    __syncthreads();
    if (threadIdx.x == 0) {
        float S1 = r1[0] + r1[1] + r1[2] + r1[3];
        float S2 = r2[0] + r2[1] + r2[2] + r2[3];
        float mean = S1 * (1.f / 512.f);
        float var  = S2 * (1.f / 512.f) - mean * mean;
        float A = g2[kd] * rsqrtf(var + EPS_BN);
        h2st[kd] = A;
        h2st[64 + kd] = b2[kd] - mean * A;
    }
}

// ---------------------------------------------------------------------------
// Kernel 5: per-b classifier: softsign(bn(h2)) -> relu(64x32) -> 32x40
// ---------------------------------------------------------------------------
__global__ __launch_bounds__(64) void k_cls(
    const float* __restrict__ h2_raw, const float* __restrict__ h2st,
    const float* __restrict__ Wc1, const float* __restrict__ bc1,
    const float* __restrict__ Wc2, const float* __restrict__ bc2,
    float* __restrict__ out)
{
    __shared__ float flat[64];
    __shared__ float hid[32];
    const int b = blockIdx.x, l = threadIdx.x;
    const int k = l >> 5, d = l & 31;     // flat index i = k*32+d = l (concat order)
    float v = h2_raw[(b * 2 + k) * 32 + d];
    flat[l] = softsignf(v * h2st[l] + h2st[64 + l]);
    __syncthreads();
    if (l < 32) {
        float a = bc1[l];
        #pragma unroll
        for (int i = 0; i < 64; ++i) a += flat[i] * Wc1[i * 32 + l];
        hid[l] = fmaxf(a, 0.f);
    }
    __syncthreads();
    if (l < NCLS) {
        float a = bc2[l];
        #pragma unroll
        for (int j = 0; j < 32; ++j) a += hid[j] * Wc2[j * NCLS + l];
        out[b * NCLS + l] = a;
    }
}

// ---------------------------------------------------------------------------
extern "C" void kernel_launch(void* const* d_in, const int* in_sizes, int n_in,
                              void* d_out, int out_size, void* d_ws, size_t ws_size,
                              hipStream_t stream)
{
    const float* x   = (const float*)d_in[0];
    const float* nbg = (const float*)d_in[1];
    const float* W1  = (const float*)d_in[2];
    const float* g1  = (const float*)d_in[3];
    const float* b1  = (const float*)d_in[4];
    const float* W2  = (const float*)d_in[5];
    const float* g2  = (const float*)d_in[6];
    const float* b2  = (const float*)d_in[7];
    const float* Wc1 = (const float*)d_in[8];
    const float* bc1 = (const float*)d_in[9];
    const float* Wc2 = (const float*)d_in[10];
    const float* bc2 = (const float*)d_in[11];
    float* out = (float*)d_out;
    float* ws  = (float*)d_ws;

    // workspace layout (floats): total ~164k floats = 656 KB
    float* h_raw  = ws;                  // B*K*64   = 65536
    float* nbs    = ws + 65536;          // B*K*64   = 65536
    float* hstats = ws + 131072;         // 16 (pad 64)
    float* h2_raw = ws + 131136;         // B*K*32   = 32768
    float* h2st   = ws + 163904;         // 128

    hipLaunchKernelGGL(k_main,    dim3(B_SZ * KHOP), dim3(256), SMEM_MAIN, stream,
                       x, nbg, W1, g1, b1, h_raw, nbs);
    hipLaunchKernelGGL(k_hstats,  dim3(KHOP * C1),   dim3(256), 0, stream,
                       h_raw, g1, b1, hstats);
    hipLaunchKernelGGL(k_stage2,  dim3(B_SZ * KHOP / 4), dim3(256), 0, stream,
                       h_raw, nbs, hstats, W2, h2_raw);
    hipLaunchKernelGGL(k_h2stats, dim3(KHOP * C2),   dim3(256), 0, stream,
                       h2_raw, g2, b2, h2st);
    hipLaunchKernelGGL(k_cls,     dim3(B_SZ),        dim3(64), 0, stream,
                       h2_raw, h2st, Wc1, bc1, Wc2, bc2, out);
}

// Round 2
// 310.651 us; speedup vs baseline: 2.0033x; 2.0033x over previous
//
#include <hip/hip_runtime.h>
#include <hip/hip_bf16.h>

#define B_SZ 512
#define KHOP 2
#define NNB  32
#define F0   512
#define C1   4
#define F1   16
#define C2   32
#define NCLS 40

#define EPS_BN   1e-5f
#define EPS_NORM 1e-7f

typedef __attribute__((ext_vector_type(8))) short short8;
typedef __attribute__((ext_vector_type(8))) unsigned short us8;
typedef __attribute__((ext_vector_type(4))) float f32x4;

__device__ __forceinline__ float softsignf(float v) { return v / (1.0f + fabsf(v)); }

__device__ __forceinline__ unsigned short f2bf(float f) {
    __hip_bfloat16 h = __float2bfloat16(f);   // RNE
    unsigned short u;
    __builtin_memcpy(&u, &h, 2);
    return u;
}

// ---------------------------------------------------------------------------
// Prep: W1 (K,C1,1,F0,F1) fp32 -> W1T bf16 [k][de=d*16+e][g]  (B-operand for
// phase-3 MFMA, read as 16B frags straight from L2).
// ---------------------------------------------------------------------------
__global__ __launch_bounds__(256) void k_prep(const float* __restrict__ W1,
                                              unsigned short* __restrict__ w1t)
{
    const int idx = blockIdx.x * 256 + threadIdx.x;   // [0, 65536)
    const int g  = idx & 511;
    const int de = (idx >> 9) & 63;
    const int kk = idx >> 15;
    const int d = de >> 4, e = de & 15;
    w1t[idx] = f2bf(W1[((size_t)((kk * 4 + d) * 512) + g) * 16 + e]);
}

// ---------------------------------------------------------------------------
// Kernel 1 (per (b,k) block, 256 thr): MFMA-based.
// LDS (74752 B):
//   [0,32768)      A: nb bf16 [32 n][512 f], swizzled (byte = n*1024 + (2f ^ ((n&7)<<4)))
//                  -> reused as A': xg bf16 [32 n][512 g], same swizzle
//   [32768,65536)  Vt strip: bf16 [512 g][32 f], byte = g*64 + (2fl ^ (((g>>1)&3)<<4))
//   [65536,67584)  xl  (x fp32, 512)
//   [67584,69632)  sl  (s fp32, 512)
//   [69632,71680)  invD fp32 512
//   [71680,73728)  xgx  fp32 512  (normalized x-row of xg)
//   [73728,74752)  redh fp32 256
// ---------------------------------------------------------------------------
#define SMEM_MAIN 74752

__global__ __launch_bounds__(256, 2) void k_main(
    const float* __restrict__ xg_, const float* __restrict__ nbg,
    const float* __restrict__ W1, const unsigned short* __restrict__ w1t,
    const float* __restrict__ g1, const float* __restrict__ b1,
    float* __restrict__ h_raw, float* __restrict__ nbs_out)
{
    extern __shared__ char smem[];
    float* xl   = (float*)(smem + 65536);
    float* sl   = (float*)(smem + 67584);
    float* invD = (float*)(smem + 69632);
    float* xgx  = (float*)(smem + 71680);
    float* redh = (float*)(smem + 73728);

    const int t = threadIdx.x;
    const int pair = blockIdx.x;          // b*2 + k
    const int b = pair >> 1, k = pair & 1;
    const int l = t & 63, w = t >> 6;

    // ---- staging: nb -> bf16 A (swizzled) + s (fp32) ; x -> xl ----
    {
        const float* nbp = nbg + (size_t)pair * (NNB * F0);
        float s0 = 0.f, s1 = 0.f;
        #pragma unroll
        for (int n = 0; n < NNB; ++n) {
            float v0 = nbp[n * F0 + t];
            float v1 = nbp[n * F0 + t + 256];
            s0 += v0; s1 += v1;
            *(unsigned short*)(smem + n * 1024 + ((2 * t) ^ ((n & 7) << 4))) = f2bf(v0);
            *(unsigned short*)(smem + n * 1024 + ((2 * (t + 256)) ^ ((n & 7) << 4))) = f2bf(v1);
        }
        sl[t] = s0; sl[t + 256] = s1;
        xl[t] = xg_[b * F0 + t];
        xl[t + 256] = xg_[b * F0 + t + 256];
    }
    __syncthreads();

    // per-thread owned columns (fixed across strips; colsum/x-row in regs)
    const int gA = t, gB = t + 256;
    const float xa = xl[gA], xb = xl[gB];
    const float sa = sl[gA], sb = sl[gB];
    float accDa = 0.f, accXa = 0.f, accDb = 0.f, accXb = 0.f;

    f32x4 acc[2][8];
    #pragma unroll
    for (int m = 0; m < 2; ++m)
        #pragma unroll
        for (int j = 0; j < 8; ++j)
            acc[m][j] = (f32x4){0.f, 0.f, 0.f, 0.f};

    const int swA = ((gA >> 1) & 3) << 4;
    const int swB = ((gB >> 1) & 3) << 4;
    const int kol = l >> 4;               // k-octet of this lane in a frag

    #pragma unroll 1
    for (int strip = 0; strip < 16; ++strip) {
        const int f0 = strip * 32;
        // ---- V-строй: thread computes V[f0..f0+31][gA,gB], writes bf16 Vt ----
        #pragma unroll
        for (int ko = 0; ko < 4; ++ko) {
            float4 xf0 = ((const float4*)xl)[(f0 >> 2) + ko * 2];
            float4 xf1 = ((const float4*)xl)[(f0 >> 2) + ko * 2 + 1];
            float4 sf0 = ((const float4*)sl)[(f0 >> 2) + ko * 2];
            float4 sf1 = ((const float4*)sl)[(f0 >> 2) + ko * 2 + 1];
            const float xf[8] = {xf0.x, xf0.y, xf0.z, xf0.w, xf1.x, xf1.y, xf1.z, xf1.w};
            const float sf[8] = {sf0.x, sf0.y, sf0.z, sf0.w, sf1.x, sf1.y, sf1.z, sf1.w};
            us8 va, vb;
            #pragma unroll
            for (int i = 0; i < 8; ++i) {
                float r1 = xf[i] * sa + xa * sf[i];
                float a1 = sqrtf(fabsf(r1));
                accDa += a1;
                float v1 = copysignf(a1, r1);
                accXa += xf[i] * v1;
                va[i] = f2bf(v1);
                float r2 = xf[i] * sb + xb * sf[i];
                float a2 = sqrtf(fabsf(r2));
                accDb += a2;
                float v2 = copysignf(a2, r2);
                accXb += xf[i] * v2;
                vb[i] = f2bf(v2);
            }
            *(us8*)(smem + 32768 + gA * 64 + ((ko * 16) ^ swA)) = va;
            *(us8*)(smem + 32768 + gB * 64 + ((ko * 16) ^ swB)) = vb;
        }
        __syncthreads();
        // ---- MFMA: C[n][g] += A[n][f-strip] * Vt[g][f-strip]^T ----
        short8 afrag[2];
        #pragma unroll
        for (int m = 0; m < 2; ++m) {
            const int n = m * 16 + (l & 15);
            afrag[m] = *(const short8*)(smem + n * 1024 +
                        ((f0 * 2 + kol * 16) ^ ((n & 7) << 4)));
        }
        #pragma unroll
        for (int j = 0; j < 8; ++j) {
            const int g = w * 128 + j * 16 + (l & 15);
            short8 bfrag = *(const short8*)(smem + 32768 + g * 64 +
                            ((kol * 16) ^ (((g >> 1) & 3) << 4)));
            acc[0][j] = __builtin_amdgcn_mfma_f32_16x16x32_bf16(afrag[0], bfrag, acc[0][j], 0, 0, 0);
            acc[1][j] = __builtin_amdgcn_mfma_f32_16x16x32_bf16(afrag[1], bfrag, acc[1][j], 0, 0, 0);
        }
        __syncthreads();
    }

    // ---- column norm factors + normalized x-row ----
    {
        const float ia = 1.f / (accDa + EPS_NORM);
        const float ib = 1.f / (accDb + EPS_NORM);
        invD[gA] = ia; xgx[gA] = accXa * ia;
        invD[gB] = ib; xgx[gB] = accXb * ib;
    }
    __syncthreads();

    // ---- A' = bf16(xg * invD), overwriting A region (nb dead) ----
    #pragma unroll
    for (int m = 0; m < 2; ++m)
        #pragma unroll
        for (int j = 0; j < 8; ++j) {
            const int g = w * 128 + j * 16 + (l & 15);
            const float iv = invD[g];
            #pragma unroll
            for (int r = 0; r < 4; ++r) {
                const int n = m * 16 + (l >> 4) * 4 + r;
                *(unsigned short*)(smem + n * 1024 + ((2 * g) ^ ((n & 7) << 4))) =
                    f2bf(acc[m][j][r] * iv);
            }
        }
    __syncthreads();

    // ---- phase 3 MFMA: nbh[n][de] = sum_g A'[n][g] * W1T[k][de][g] ----
    f32x4 acc3[2];
    acc3[0] = (f32x4){0.f, 0.f, 0.f, 0.f};
    acc3[1] = (f32x4){0.f, 0.f, 0.f, 0.f};
    {
        const int de = w * 16 + (l & 15);
        const unsigned short* wtp = w1t + ((size_t)(k * 64 + de) * 512) + kol * 8;
        #pragma unroll
        for (int ks = 0; ks < 16; ++ks) {
            short8 bfrag = *(const short8*)(wtp + ks * 32);
            #pragma unroll
            for (int m = 0; m < 2; ++m) {
                const int n = m * 16 + (l & 15);
                short8 af = *(const short8*)(smem + n * 1024 +
                            ((ks * 64 + kol * 16) ^ ((n & 7) << 4)));
                acc3[m] = __builtin_amdgcn_mfma_f32_16x16x32_bf16(af, bfrag, acc3[m], 0, 0, 0);
            }
        }
    }

    // ---- nbh BN (per d=w over all 512 (n,e)) + softsign + sum over n — in-register ----
    {
        float vals[8];
        float s1 = 0.f, s2 = 0.f;
        #pragma unroll
        for (int m = 0; m < 2; ++m)
            #pragma unroll
            for (int r = 0; r < 4; ++r) {
                float v = acc3[m][r];
                vals[m * 4 + r] = v; s1 += v; s2 += v * v;
            }
        #pragma unroll
        for (int off = 32; off >= 1; off >>= 1) {
            s1 += __shfl_xor(s1, off);
            s2 += __shfl_xor(s2, off);
        }
        const float mean = s1 * (1.f / 512.f);
        const float var  = s2 * (1.f / 512.f) - mean * mean;
        const float An   = g1[k * C1 + w] * rsqrtf(var + EPS_BN);
        const float Bn   = b1[k * C1 + w] - mean * An;
        float nbse = 0.f;
        #pragma unroll
        for (int i = 0; i < 8; ++i) nbse += softsignf(vals[i] * An + Bn);
        nbse += __shfl_xor(nbse, 16);   // vals share e=l&15; reduce over n-groups
        nbse += __shfl_xor(nbse, 32);
        if (l < 16) nbs_out[pair * 64 + w * 16 + l] = nbse;
    }

    // ---- h path (fp32): h[de] = sum_g xgx[g] * W1[k,d,g,e] ----
    {
        const int de2 = t & 63, gs = t >> 6;
        const int d = de2 >> 4, e = de2 & 15;
        const float* Wp = W1 + ((size_t)(k * 4 + d) * 512) * 16 + e;
        float acch = 0.f;
        const int gbeg = gs * 128;
        #pragma unroll 8
        for (int gi = 0; gi < 128; ++gi)
            acch += xgx[gbeg + gi] * Wp[(gbeg + gi) * 16];
        redh[gs * 64 + de2] = acch;
    }
    __syncthreads();
    if (t < 64)
        h_raw[pair * 64 + t] = redh[t] + redh[64 + t] + redh[128 + t] + redh[192 + t];
}

// ---------------------------------------------------------------------------
// Kernel 2: global BN stats for h over (b,e) per (k,d). Writes affine (A,B).
// ---------------------------------------------------------------------------
__global__ __launch_bounds__(256) void k_hstats(
    const float* __restrict__ h_rawg, const float* __restrict__ g1,
    const float* __restrict__ b1, float* __restrict__ hstats)
{
    const int kd = blockIdx.x;           // k*4+d
    const int k = kd >> 2, d = kd & 3;
    float s1 = 0.f, s2 = 0.f;
    for (int i = threadIdx.x; i < B_SZ * F1; i += 256) {
        const int bb = i >> 4, e = i & 15;
        float v = h_rawg[(bb * 2 + k) * 64 + d * 16 + e];
        s1 += v; s2 += v * v;
    }
    #pragma unroll
    for (int off = 32; off >= 1; off >>= 1) { s1 += __shfl_xor(s1, off); s2 += __shfl_xor(s2, off); }
    __shared__ float r1[4], r2[4];
    if ((threadIdx.x & 63) == 0) { r1[threadIdx.x >> 6] = s1; r2[threadIdx.x >> 6] = s2; }
    __syncthreads();
    if (threadIdx.x == 0) {
        float S1 = r1[0] + r1[1] + r1[2] + r1[3];
        float S2 = r2[0] + r2[1] + r2[2] + r2[3];
        float mean = S1 * (1.f / 8192.f);
        float var  = S2 * (1.f / 8192.f) - mean * mean;
        float A = g1[kd] * rsqrtf(var + EPS_BN);
        hstats[kd] = A;
        hstats[8 + kd] = b1[kd] - mean * A;
    }
}

// ---------------------------------------------------------------------------
// Kernel 3: per (b,k) wave: softsign(bn(h)), fadj2 (16x16), xg2, W2 -> h2_raw
// ---------------------------------------------------------------------------
__global__ __launch_bounds__(256) void k_stage2(
    const float* __restrict__ h_rawg, const float* __restrict__ nbsg,
    const float* __restrict__ hstats, const float* __restrict__ W2,
    float* __restrict__ h2_raw)
{
    __shared__ float hl[4][64], nl[4][64], fl[4][256], xg2l[4][64];
    const int t = threadIdx.x, wv = t >> 6, l = t & 63;
    const int pair = blockIdx.x * 4 + wv;
    const int k = pair & 1;
    const int d = l >> 4;
    float hv = h_rawg[pair * 64 + l];
    hl[wv][l] = softsignf(hv * hstats[k * 4 + d] + hstats[8 + k * 4 + d]);
    nl[wv][l] = nbsg[pair * 64 + l];
    __syncthreads();
    const int gcol = l & 15;
    float raw[4];
    #pragma unroll
    for (int j = 0; j < 4; ++j) {
        const int idx = l + 64 * j;       // idx = f*16+g (g == gcol)
        const int f = idx >> 4;
        float a = 0.f;
        #pragma unroll
        for (int c = 0; c < 4; ++c) a += hl[wv][c * 16 + f] * nl[wv][c * 16 + gcol];
        raw[j] = a;
        fl[wv][idx] = a;
    }
    __syncthreads();
    float w4[4]; float Dp = 0.f;
    #pragma unroll
    for (int j = 0; j < 4; ++j) {
        const int idx = l + 64 * j;
        const int f = idx >> 4;
        float v = raw[j] + fl[wv][gcol * 16 + f];   // symmetrize
        float a = sqrtf(fabsf(v));
        Dp += a;
        w4[j] = copysignf(a, v);
    }
    Dp += __shfl_xor(Dp, 16);   // column sum over f (lanes sharing gcol)
    Dp += __shfl_xor(Dp, 32);
    const float invD = 1.f / (Dp + EPS_NORM);
    __syncthreads();            // transposed reads done before overwrite
    #pragma unroll
    for (int j = 0; j < 4; ++j) fl[wv][l + 64 * j] = w4[j] * invD;
    __syncthreads();
    {
        const int c = l >> 4;
        float a = 0.f;
        #pragma unroll
        for (int f = 0; f < 16; ++f) a += hl[wv][c * 16 + f] * fl[wv][f * 16 + gcol];
        xg2l[wv][c * 16 + gcol] = a;
    }
    __syncthreads();
    if (l < 32) {
        const float* W2p = W2 + k * (C2 * C1 * F1) + l * (C1 * F1);
        float a = 0.f;
        #pragma unroll
        for (int i = 0; i < 64; ++i) a += xg2l[wv][i] * W2p[i];
        h2_raw[pair * 32 + l] = a;
    }
}

// ---------------------------------------------------------------------------
// Kernel 4: global BN stats for h2 over b per (k,d=32)
// ---------------------------------------------------------------------------
__global__ __launch_bounds__(256) void k_h2stats(
    const float* __restrict__ h2_raw, const float* __restrict__ g2,
    const float* __restrict__ b2, float* __restrict__ h2st)
{
    const int kd = blockIdx.x;           // k*32+d
    const int k = kd >> 5, d = kd & 31;
    float s1 = 0.f, s2 = 0.f;
    for (int bb = threadIdx.x; bb < B_SZ; bb += 256) {
        float v = h2_raw[(bb * 2 + k) * 32 + d];
        s1 += v; s2 += v * v;
    }
    #pragma unroll
    for (int off = 32; off >= 1; off >>= 1) { s1 += __shfl_xor(s1, off); s2 += __shfl_xor(s2, off); }
    __shared__ float r1[4], r2[4];
    if ((threadIdx.x & 63) == 0) { r1[threadIdx.x >> 6] = s1; r2[threadIdx.x >> 6] = s2; }
    __syncthreads();
    if (threadIdx.x == 0) {
        float S1 = r1[0] + r1[1] + r1[2] + r1[3];
        float S2 = r2[0] + r2[1] + r2[2] + r2[3];
        float mean = S1 * (1.f / 512.f);
        float var  = S2 * (1.f / 512.f) - mean * mean;
        float A = g2[kd] * rsqrtf(var + EPS_BN);
        h2st[kd] = A;
        h2st[64 + kd] = b2[kd] - mean * A;
    }
}

// ---------------------------------------------------------------------------
// Kernel 5: per-b classifier: softsign(bn(h2)) -> relu(64x32) -> 32x40
// ---------------------------------------------------------------------------
__global__ __launch_bounds__(64) void k_cls(
    const float* __restrict__ h2_raw, const float* __restrict__ h2st,
    const float* __restrict__ Wc1, const float* __restrict__ bc1,
    const float* __restrict__ Wc2, const float* __restrict__ bc2,
    float* __restrict__ out)
{
    __shared__ float flat[64];
    __shared__ float hid[32];
    const int b = blockIdx.x, l = threadIdx.x;
    const int k = l >> 5, d = l & 31;     // flat index i = k*32+d = l (concat order)
    float v = h2_raw[(b * 2 + k) * 32 + d];
    flat[l] = softsignf(v * h2st[l] + h2st[64 + l]);
    __syncthreads();
    if (l < 32) {
        float a = bc1[l];
        #pragma unroll
        for (int i = 0; i < 64; ++i) a += flat[i] * Wc1[i * 32 + l];
        hid[l] = fmaxf(a, 0.f);
    }
    __syncthreads();
    if (l < NCLS) {
        float a = bc2[l];
        #pragma unroll
        for (int j = 0; j < 32; ++j) a += hid[j] * Wc2[j * NCLS + l];
        out[b * NCLS + l] = a;
    }
}

// ---------------------------------------------------------------------------
extern "C" void kernel_launch(void* const* d_in, const int* in_sizes, int n_in,
                              void* d_out, int out_size, void* d_ws, size_t ws_size,
                              hipStream_t stream)
{
    const float* x   = (const float*)d_in[0];
    const float* nbg = (const float*)d_in[1];
    const float* W1  = (const float*)d_in[2];
    const float* g1  = (const float*)d_in[3];
    const float* b1  = (const float*)d_in[4];
    const float* W2  = (const float*)d_in[5];
    const float* g2  = (const float*)d_in[6];
    const float* b2  = (const float*)d_in[7];
    const float* Wc1 = (const float*)d_in[8];
    const float* bc1 = (const float*)d_in[9];
    const float* Wc2 = (const float*)d_in[10];
    const float* bc2 = (const float*)d_in[11];
    float* out = (float*)d_out;
    float* ws  = (float*)d_ws;

    // workspace layout (floats): total ~164k floats = 656 KB
    float* h_raw  = ws;                   // B*K*64   = 65536
    float* nbs    = ws + 65536;           // B*K*64   = 65536
    float* hstats = ws + 131072;          // 16 (pad 64)
    float* h2_raw = ws + 131136;          // B*K*32   = 32768 (131072 B)
    float* h2st   = ws + 163904;          // 128
    // w1t (bf16, 2*64*512 = 65536 ushorts = 131072 B) ALIASES h2_raw:
    // w1t is consumed only inside k_main; h2_raw is written only by k_stage2,
    // which runs after k_main on the same stream. No overlap in lifetime.
    unsigned short* w1t = (unsigned short*)h2_raw;

    hipLaunchKernelGGL(k_prep,    dim3(256),            dim3(256), 0, stream, W1, w1t);
    hipLaunchKernelGGL(k_main,    dim3(B_SZ * KHOP),    dim3(256), SMEM_MAIN, stream,
                       x, nbg, W1, w1t, g1, b1, h_raw, nbs);
    hipLaunchKernelGGL(k_hstats,  dim3(KHOP * C1),      dim3(256), 0, stream,
                       h_raw, g1, b1, hstats);
    hipLaunchKernelGGL(k_stage2,  dim3(B_SZ * KHOP / 4), dim3(256), 0, stream,
                       h_raw, nbs, hstats, W2, h2_raw);
    hipLaunchKernelGGL(k_h2stats, dim3(KHOP * C2),      dim3(256), 0, stream,
                       h2_raw, g2, b2, h2st);
    hipLaunchKernelGGL(k_cls,     dim3(B_SZ),           dim3(64), 0, stream,
                       h2_raw, h2st, Wc1, bc1, Wc2, bc2, out);
}

// Round 3
// 305.561 us; speedup vs baseline: 2.0366x; 1.0167x over previous
//
#include <hip/hip_runtime.h>
#include <hip/hip_bf16.h>

#define B_SZ 512
#define KHOP 2
#define NNB  32
#define F0   512
#define C1   4
#define F1   16
#define C2   32
#define NCLS 40

#define EPS_BN   1e-5f
#define EPS_NORM 1e-7f

typedef __attribute__((ext_vector_type(8))) short short8;
typedef __attribute__((ext_vector_type(4))) float f32x4;

__device__ __forceinline__ float softsignf(float v) { return v / (1.0f + fabsf(v)); }

// HW packed f32->bf16 (RNE). lo -> bits[15:0], hi -> bits[31:16].
__device__ __forceinline__ unsigned cvt_pk_bf16(float lo, float hi) {
    unsigned r;
    asm("v_cvt_pk_bf16_f32 %0, %1, %2" : "=v"(r) : "v"(lo), "v"(hi));
    return r;
}

// ---------------------------------------------------------------------------
// Kernel 1 (per (b,k) block, 256 thr): MFMA-based.
// LDS (74752 B):
//   [0,32768)      A: nb bf16 [32 n][512 f], swizzled (byte = n*1024 + (2f ^ ((n&7)<<4)))
//                  -> reused as A': xg bf16 [32 n][512 g], same swizzle
//   [32768,65536)  Vt strip: bf16 [512 g][32 f], byte = g*64 + (2fl ^ (((g>>1)&3)<<4))
//                  (also used transiently as s-partials fp32 [4][512] during staging)
//   [65536,67584)  xl  (x fp32, 512)
//   [67584,69632)  sl  (s fp32, 512)
//   [69632,71680)  invD fp32 512
//   [71680,73728)  xgx  fp32 512  (normalized x-row of xg)
//   [73728,74752)  redh fp32 256
// ---------------------------------------------------------------------------
#define SMEM_MAIN 74752

__global__ __launch_bounds__(256, 2) void k_main(
    const float* __restrict__ xg_, const float* __restrict__ nbg,
    const float* __restrict__ W1,
    const float* __restrict__ g1, const float* __restrict__ b1,
    float* __restrict__ h_raw, float* __restrict__ nbs_out,
    float* __restrict__ hsum)
{
    extern __shared__ char smem[];
    float* xl   = (float*)(smem + 65536);
    float* sl   = (float*)(smem + 67584);
    float* invD = (float*)(smem + 69632);
    float* xgx  = (float*)(smem + 71680);
    float* redh = (float*)(smem + 73728);

    const int t = threadIdx.x;
    const int pair = blockIdx.x;          // b*2 + k
    const int b = pair >> 1, k = pair & 1;
    const int l = t & 63, w = t >> 6;

    // ---- staging: nb -> bf16 A (swizzled, b128 writes) + fp32 s-partials ----
    {
        const int oct = t & 63, ng = t >> 6;
        const int f0s = oct * 8;
        const float* nbp = nbg + (size_t)pair * (NNB * F0);
        float sp0=0,sp1=0,sp2=0,sp3=0,sp4=0,sp5=0,sp6=0,sp7=0;
        #pragma unroll
        for (int ni = 0; ni < 8; ++ni) {
            const int n = ng * 8 + ni;
            float4 q0 = *(const float4*)(nbp + n * F0 + f0s);
            float4 q1 = *(const float4*)(nbp + n * F0 + f0s + 4);
            sp0 += q0.x; sp1 += q0.y; sp2 += q0.z; sp3 += q0.w;
            sp4 += q1.x; sp5 += q1.y; sp6 += q1.z; sp7 += q1.w;
            uint4 p;
            p.x = cvt_pk_bf16(q0.x, q0.y);
            p.y = cvt_pk_bf16(q0.z, q0.w);
            p.z = cvt_pk_bf16(q1.x, q1.y);
            p.w = cvt_pk_bf16(q1.z, q1.w);
            *(uint4*)(smem + n * 1024 + ((2 * f0s) ^ ((n & 7) << 4))) = p;
        }
        float* part = (float*)(smem + 32768);
        *(float4*)(part + ng * 512 + f0s)     = make_float4(sp0, sp1, sp2, sp3);
        *(float4*)(part + ng * 512 + f0s + 4) = make_float4(sp4, sp5, sp6, sp7);
        xl[t]       = xg_[b * F0 + t];
        xl[t + 256] = xg_[b * F0 + t + 256];
    }
    __syncthreads();
    {   // gather s[f] from 4 n-group partials (fp32, matches R2 numerics)
        const float* part = (const float*)(smem + 32768);
        float sA = part[t] + part[512 + t] + part[1024 + t] + part[1536 + t];
        float sB = part[t + 256] + part[512 + t + 256]
                 + part[1024 + t + 256] + part[1536 + t + 256];
        sl[t] = sA; sl[t + 256] = sB;
    }
    __syncthreads();

    // per-thread owned columns
    const int gA = t, gB = t + 256;
    const float xa = xl[gA], xb = xl[gB];
    const float sa = sl[gA], sb = sl[gB];
    float dA0=0.f, dA1=0.f, dB0=0.f, dB1=0.f;       // col |V| sums (2 partials)
    float xA0=0.f, xA1=0.f, xB0=0.f, xB1=0.f;       // x-row of xg (2 partials)

    f32x4 acc[2][8];
    #pragma unroll
    for (int m = 0; m < 2; ++m)
        #pragma unroll
        for (int j = 0; j < 8; ++j)
            acc[m][j] = (f32x4){0.f, 0.f, 0.f, 0.f};

    const int swA = ((gA >> 1) & 3) << 4;
    const int swB = ((gB >> 1) & 3) << 4;
    const int kol = l >> 4;

    #pragma unroll 1
    for (int strip = 0; strip < 16; ++strip) {
        const int f0 = strip * 32;
        // ---- V construction: V[f0..f0+31][gA,gB] -> bf16 Vt (packed stores) ----
        #pragma unroll
        for (int ko = 0; ko < 4; ++ko) {
            float4 xf0 = ((const float4*)xl)[(f0 >> 2) + ko * 2];
            float4 xf1 = ((const float4*)xl)[(f0 >> 2) + ko * 2 + 1];
            float4 sf0 = ((const float4*)sl)[(f0 >> 2) + ko * 2];
            float4 sf1 = ((const float4*)sl)[(f0 >> 2) + ko * 2 + 1];
            const float xf[8] = {xf0.x, xf0.y, xf0.z, xf0.w, xf1.x, xf1.y, xf1.z, xf1.w};
            const float sf[8] = {sf0.x, sf0.y, sf0.z, sf0.w, sf1.x, sf1.y, sf1.z, sf1.w};
            uint pa[4], pb[4];
            float vpA = 0.f, vpB = 0.f;
            #pragma unroll
            for (int i = 0; i < 8; ++i) {
                float rA = xf[i] * sa + xa * sf[i];
                float aA = sqrtf(fabsf(rA));
                float vA = copysignf(aA, rA);
                float rB = xf[i] * sb + xb * sf[i];
                float aB = sqrtf(fabsf(rB));
                float vB = copysignf(aB, rB);
                if (i & 1) {
                    dA1 += aA; dB1 += aB; xA1 += xf[i] * vA; xB1 += xf[i] * vB;
                    pa[i >> 1] = cvt_pk_bf16(vpA, vA);
                    pb[i >> 1] = cvt_pk_bf16(vpB, vB);
                } else {
                    dA0 += aA; dB0 += aB; xA0 += xf[i] * vA; xB0 += xf[i] * vB;
                    vpA = vA; vpB = vB;
                }
            }
            uint4 ua; ua.x = pa[0]; ua.y = pa[1]; ua.z = pa[2]; ua.w = pa[3];
            uint4 ub; ub.x = pb[0]; ub.y = pb[1]; ub.z = pb[2]; ub.w = pb[3];
            *(uint4*)(smem + 32768 + gA * 64 + ((ko * 16) ^ swA)) = ua;
            *(uint4*)(smem + 32768 + gB * 64 + ((ko * 16) ^ swB)) = ub;
        }
        __syncthreads();
        // ---- MFMA: C[n][g] += A[n][f-strip] * Vt[g][f-strip]^T ----
        short8 afrag[2];
        #pragma unroll
        for (int m = 0; m < 2; ++m) {
            const int n = m * 16 + (l & 15);
            afrag[m] = *(const short8*)(smem + n * 1024 +
                        ((f0 * 2 + kol * 16) ^ ((n & 7) << 4)));
        }
        #pragma unroll
        for (int j = 0; j < 8; ++j) {
            const int g = w * 128 + j * 16 + (l & 15);
            short8 bfrag = *(const short8*)(smem + 32768 + g * 64 +
                            ((kol * 16) ^ (((g >> 1) & 3) << 4)));
            acc[0][j] = __builtin_amdgcn_mfma_f32_16x16x32_bf16(afrag[0], bfrag, acc[0][j], 0, 0, 0);
            acc[1][j] = __builtin_amdgcn_mfma_f32_16x16x32_bf16(afrag[1], bfrag, acc[1][j], 0, 0, 0);
        }
        __syncthreads();
    }

    // ---- column norm factors + normalized x-row ----
    {
        const float ia = 1.f / ((dA0 + dA1) + EPS_NORM);
        const float ib = 1.f / ((dB0 + dB1) + EPS_NORM);
        invD[gA] = ia; xgx[gA] = (xA0 + xA1) * ia;
        invD[gB] = ib; xgx[gB] = (xB0 + xB1) * ib;
    }
    __syncthreads();

    // ---- A' = bf16(xg * invD), overwriting A region (nb dead) ----
    #pragma unroll
    for (int m = 0; m < 2; ++m)
        #pragma unroll
        for (int j = 0; j < 8; ++j) {
            const int g = w * 128 + j * 16 + (l & 15);
            const float iv = invD[g];
            #pragma unroll
            for (int r = 0; r < 4; ++r) {
                const int n = m * 16 + (l >> 4) * 4 + r;
                unsigned pv = cvt_pk_bf16(acc[m][j][r] * iv, 0.f);
                *(unsigned short*)(smem + n * 1024 + ((2 * g) ^ ((n & 7) << 4))) =
                    (unsigned short)pv;
            }
        }
    __syncthreads();

    // ---- phase 3 MFMA: nbh[n][de] = sum_g A'[n][g] * bf16(W1[k,d,g,e]) ----
    f32x4 acc3[2];
    acc3[0] = (f32x4){0.f, 0.f, 0.f, 0.f};
    acc3[1] = (f32x4){0.f, 0.f, 0.f, 0.f};
    {
        const int de = w * 16 + (l & 15);
        const int d3 = de >> 4, e3 = de & 15;
        const float* Wp3 = W1 + ((k * 4 + d3) * 512) * 16 + e3;
        #pragma unroll 2
        for (int ks = 0; ks < 16; ++ks) {
            const int gg0 = ks * 32 + kol * 8;
            float w0 = Wp3[(gg0 + 0) * 16], w1 = Wp3[(gg0 + 1) * 16];
            float w2 = Wp3[(gg0 + 2) * 16], w3 = Wp3[(gg0 + 3) * 16];
            float w4 = Wp3[(gg0 + 4) * 16], w5 = Wp3[(gg0 + 5) * 16];
            float w6 = Wp3[(gg0 + 6) * 16], w7 = Wp3[(gg0 + 7) * 16];
            uint4 bp;
            bp.x = cvt_pk_bf16(w0, w1); bp.y = cvt_pk_bf16(w2, w3);
            bp.z = cvt_pk_bf16(w4, w5); bp.w = cvt_pk_bf16(w6, w7);
            short8 bfrag;
            __builtin_memcpy(&bfrag, &bp, 16);
            #pragma unroll
            for (int m = 0; m < 2; ++m) {
                const int n = m * 16 + (l & 15);
                short8 af = *(const short8*)(smem + n * 1024 +
                            ((ks * 64 + kol * 16) ^ ((n & 7) << 4)));
                acc3[m] = __builtin_amdgcn_mfma_f32_16x16x32_bf16(af, bfrag, acc3[m], 0, 0, 0);
            }
        }
    }

    // ---- nbh BN (per d=w over 512 (n,e)) + softsign + sum over n — in-register ----
    {
        float vals[8];
        float s1 = 0.f, s2 = 0.f;
        #pragma unroll
        for (int m = 0; m < 2; ++m)
            #pragma unroll
            for (int r = 0; r < 4; ++r) {
                float v = acc3[m][r];
                vals[m * 4 + r] = v; s1 += v; s2 += v * v;
            }
        #pragma unroll
        for (int off = 32; off >= 1; off >>= 1) {
            s1 += __shfl_xor(s1, off);
            s2 += __shfl_xor(s2, off);
        }
        const float mean = s1 * (1.f / 512.f);
        const float var  = s2 * (1.f / 512.f) - mean * mean;
        const float An   = g1[k * C1 + w] * rsqrtf(var + EPS_BN);
        const float Bn   = b1[k * C1 + w] - mean * An;
        float nbse = 0.f;
        #pragma unroll
        for (int i = 0; i < 8; ++i) nbse += softsignf(vals[i] * An + Bn);
        nbse += __shfl_xor(nbse, 16);
        nbse += __shfl_xor(nbse, 32);
        if (l < 16) nbs_out[pair * 64 + w * 16 + l] = nbse;
    }

    // ---- h path (fp32): h[de] = sum_g xgx[g] * W1[k,d,g,e] ----
    {
        const int de2 = t & 63, gs = t >> 6;
        const int d = de2 >> 4, e = de2 & 15;
        const float* Wp = W1 + ((k * 4 + d) * 512) * 16 + e;
        float a0 = 0.f, a1 = 0.f;
        const int gbeg = gs * 128;
        #pragma unroll 8
        for (int gi = 0; gi < 128; gi += 2) {
            a0 += xgx[gbeg + gi]     * Wp[(gbeg + gi) * 16];
            a1 += xgx[gbeg + gi + 1] * Wp[(gbeg + gi + 1) * 16];
        }
        redh[gs * 64 + de2] = a0 + a1;
    }
    __syncthreads();
    if (t < 64) {
        float hv = redh[t] + redh[64 + t] + redh[128 + t] + redh[192 + t];
        h_raw[pair * 64 + t] = hv;
        // partial BN-h stats: reduce over e (16 lanes) then atomicAdd per (k,d)
        float s1 = hv, s2 = hv * hv;
        #pragma unroll
        for (int off = 1; off <= 8; off <<= 1) {
            s1 += __shfl_xor(s1, off);
            s2 += __shfl_xor(s2, off);
        }
        if ((t & 15) == 0) {
            atomicAdd(&hsum[k * 4 + (t >> 4)], s1);
            atomicAdd(&hsum[8 + k * 4 + (t >> 4)], s2);
        }
    }
}

// ---------------------------------------------------------------------------
// Kernel 2: per (b,k) wave: softsign(bn(h)) via hsum, fadj2 (16x16), xg2,
// W2 -> h2_raw; accumulates global h2 BN stats into h2sum via atomics.
// ---------------------------------------------------------------------------
__global__ __launch_bounds__(256) void k_stage2(
    const float* __restrict__ h_rawg, const float* __restrict__ nbsg,
    const float* __restrict__ hsum,
    const float* __restrict__ g1, const float* __restrict__ b1,
    const float* __restrict__ W2,
    float* __restrict__ h2_raw, float* __restrict__ h2sum)
{
    __shared__ float hl[4][64], nl[4][64], fl[4][256], xg2l[4][64];
    const int t = threadIdx.x, wv = t >> 6, l = t & 63;
    const int pair = blockIdx.x * 4 + wv;
    const int k = pair & 1;
    const int d = l >> 4;
    {
        const float S1 = hsum[k * 4 + d], S2 = hsum[8 + k * 4 + d];
        const float mean = S1 * (1.f / 8192.f);
        const float var  = S2 * (1.f / 8192.f) - mean * mean;
        const float A = g1[k * 4 + d] * rsqrtf(var + EPS_BN);
        const float Bc = b1[k * 4 + d] - mean * A;
        float hv = h_rawg[pair * 64 + l];
        hl[wv][l] = softsignf(hv * A + Bc);
        nl[wv][l] = nbsg[pair * 64 + l];
    }
    __syncthreads();
    const int gcol = l & 15;
    float raw[4];
    #pragma unroll
    for (int j = 0; j < 4; ++j) {
        const int idx = l + 64 * j;       // idx = f*16+g (g == gcol)
        const int f = idx >> 4;
        float a = 0.f;
        #pragma unroll
        for (int c = 0; c < 4; ++c) a += hl[wv][c * 16 + f] * nl[wv][c * 16 + gcol];
        raw[j] = a;
        fl[wv][idx] = a;
    }
    __syncthreads();
    float w4[4]; float Dp = 0.f;
    #pragma unroll
    for (int j = 0; j < 4; ++j) {
        const int idx = l + 64 * j;
        const int f = idx >> 4;
        float v = raw[j] + fl[wv][gcol * 16 + f];   // symmetrize
        float a = sqrtf(fabsf(v));
        Dp += a;
        w4[j] = copysignf(a, v);
    }
    Dp += __shfl_xor(Dp, 16);
    Dp += __shfl_xor(Dp, 32);
    const float invD = 1.f / (Dp + EPS_NORM);
    __syncthreads();
    #pragma unroll
    for (int j = 0; j < 4; ++j) fl[wv][l + 64 * j] = w4[j] * invD;
    __syncthreads();
    {
        const int c = l >> 4;
        float a = 0.f;
        #pragma unroll
        for (int f = 0; f < 16; ++f) a += hl[wv][c * 16 + f] * fl[wv][f * 16 + gcol];
        xg2l[wv][c * 16 + gcol] = a;
    }
    __syncthreads();
    if (l < 32) {
        const float* W2p = W2 + k * (C2 * C1 * F1) + l * (C1 * F1);
        float a = 0.f;
        #pragma unroll
        for (int i = 0; i < 64; ++i) a += xg2l[wv][i] * W2p[i];
        h2_raw[pair * 32 + l] = a;
        atomicAdd(&h2sum[k * 32 + l], a);
        atomicAdd(&h2sum[64 + k * 32 + l], a * a);
    }
}

// ---------------------------------------------------------------------------
// Kernel 3: per-b classifier: softsign(bn(h2)) via h2sum -> relu(64x32) -> 32x40
// ---------------------------------------------------------------------------
__global__ __launch_bounds__(64) void k_cls(
    const float* __restrict__ h2_raw, const float* __restrict__ h2sum,
    const float* __restrict__ g2, const float* __restrict__ b2,
    const float* __restrict__ Wc1, const float* __restrict__ bc1,
    const float* __restrict__ Wc2, const float* __restrict__ bc2,
    float* __restrict__ out)
{
    __shared__ float flat[64];
    __shared__ float hid[32];
    const int b = blockIdx.x, l = threadIdx.x;
    const int k = l >> 5, d = l & 31;     // flat index = k*32+d = l
    {
        const float S1 = h2sum[l], S2 = h2sum[64 + l];
        const float mean = S1 * (1.f / 512.f);
        const float var  = S2 * (1.f / 512.f) - mean * mean;
        const float A = g2[l] * rsqrtf(var + EPS_BN);
        const float Bc = b2[l] - mean * A;
        float v = h2_raw[(b * 2 + k) * 32 + d];
        flat[l] = softsignf(v * A + Bc);
    }
    __syncthreads();
    if (l < 32) {
        float a = bc1[l];
        #pragma unroll
        for (int i = 0; i < 64; ++i) a += flat[i] * Wc1[i * 32 + l];
        hid[l] = fmaxf(a, 0.f);
    }
    __syncthreads();
    if (l < NCLS) {
        float a = bc2[l];
        #pragma unroll
        for (int j = 0; j < 32; ++j) a += hid[j] * Wc2[j * NCLS + l];
        out[b * NCLS + l] = a;
    }
}

// ---------------------------------------------------------------------------
extern "C" void kernel_launch(void* const* d_in, const int* in_sizes, int n_in,
                              void* d_out, int out_size, void* d_ws, size_t ws_size,
                              hipStream_t stream)
{
    const float* x   = (const float*)d_in[0];
    const float* nbg = (const float*)d_in[1];
    const float* W1  = (const float*)d_in[2];
    const float* g1  = (const float*)d_in[3];
    const float* b1  = (const float*)d_in[4];
    const float* W2  = (const float*)d_in[5];
    const float* g2  = (const float*)d_in[6];
    const float* b2  = (const float*)d_in[7];
    const float* Wc1 = (const float*)d_in[8];
    const float* bc1 = (const float*)d_in[9];
    const float* Wc2 = (const float*)d_in[10];
    const float* bc2 = (const float*)d_in[11];
    float* out = (float*)d_out;
    float* ws  = (float*)d_ws;

    // workspace layout (floats):
    float* h_raw  = ws;                   // B*K*64 = 65536
    float* nbs    = ws + 65536;           // B*K*64 = 65536
    float* h2_raw = ws + 131072;          // B*K*32 = 32768
    float* stats  = ws + 163840;          // hsum[16] + h2sum[128] = 144
    float* hsum   = stats;
    float* h2sum  = stats + 16;

    hipMemsetAsync(stats, 0, 144 * sizeof(float), stream);
    hipLaunchKernelGGL(k_main,   dim3(B_SZ * KHOP),     dim3(256), SMEM_MAIN, stream,
                       x, nbg, W1, g1, b1, h_raw, nbs, hsum);
    hipLaunchKernelGGL(k_stage2, dim3(B_SZ * KHOP / 4), dim3(256), 0, stream,
                       h_raw, nbs, hsum, g1, b1, W2, h2_raw, h2sum);
    hipLaunchKernelGGL(k_cls,    dim3(B_SZ),            dim3(64), 0, stream,
                       h2_raw, h2sum, g2, b2, Wc1, bc1, Wc2, bc2, out);
}